// Round 2
// baseline (470.637 us; speedup 1.0000x reference)
//
#include <hip/hip_runtime.h>

typedef unsigned short u16;
typedef float f32x4 __attribute__((ext_vector_type(4)));
typedef short s16x8 __attribute__((ext_vector_type(8)));
typedef unsigned short u16x4 __attribute__((ext_vector_type(4)));

#define EPS 1e-6f

static __device__ __forceinline__ u16 f2bf(float f) {
  unsigned u = __float_as_uint(f);
  u += 0x7fffu + ((u >> 16) & 1u);   // RNE
  return (u16)(u >> 16);
}
static __device__ __forceinline__ float bf2f(u16 h) {
  return __uint_as_float(((unsigned)h) << 16);
}

// ---------------- Stage 1: transpose weights to bf16 [col][k] ----------------
__global__ void wtrans_kernel(const float* __restrict__ Wq, const float* __restrict__ Wk,
                              const float* __restrict__ Wv,
                              u16* __restrict__ WqT, u16* __restrict__ WkT, u16* __restrict__ WvT) {
  int b = blockIdx.x;
  int mat = b >> 4, cg = b & 15;
  const float* W = mat == 0 ? Wq : (mat == 1 ? Wk : Wv);
  u16* WT = mat == 0 ? WqT : (mat == 1 ? WkT : WvT);
  int t = threadIdx.x;
  int c = cg * 16 + (t & 15);
  int k0 = (t >> 4) * 16;
  for (int i = 0; i < 16; ++i) {
    int k = k0 + i;
    WT[c * 256 + k] = f2bf(W[k * 256 + c]);
  }
}

// ---------------- Stage 2: Q,K,V GEMMs, weights in REGISTERS (no inner barriers) ----------------
// Writes Qb [n][d], Kt/Vt [d][n] (bf16). Also accumulates ksum[d] = sum_n K[n][d] (fp32 atomics).
__global__ __launch_bounds__(256, 2)
void qkv_kernel(const float* __restrict__ x,
                const u16* __restrict__ WqT, const u16* __restrict__ WkT, const u16* __restrict__ WvT,
                const float* __restrict__ bq, const float* __restrict__ bk, const float* __restrict__ bv,
                u16* __restrict__ Qb, u16* __restrict__ Kt, u16* __restrict__ Vt,
                float* __restrict__ ksum, int N, int NPAD) {
  __shared__ u16 xs[128][264];   // x tile bf16, +8 pad (row stride 33 granules -> conflict-free frags)
  __shared__ float ksl[256];     // block-local K column sums
  const int tid = threadIdx.x;
  const int n0 = blockIdx.x * 128;

  ksl[tid] = 0.f;

  // stage x tile (fp32 -> bf16), zero-pad rows >= N.  Once per block.
  for (int i = 0; i < 32; ++i) {
    int l = tid + i * 256;
    int row = l >> 6;
    int c4 = (l & 63) << 2;
    int n = n0 + row;
    float4 v = make_float4(0.f, 0.f, 0.f, 0.f);
    if (n < N) v = *(const float4*)(x + (size_t)n * 256 + c4);
    xs[row][c4 + 0] = f2bf(v.x);
    xs[row][c4 + 1] = f2bf(v.y);
    xs[row][c4 + 2] = f2bf(v.z);
    xs[row][c4 + 3] = f2bf(v.w);
  }
  __syncthreads();   // the ONLY barrier before the final ksum flush

  const int wave = tid >> 6, lane = tid & 63;
  const int quad = lane >> 4, l16 = lane & 15;
  const int wr = (wave >> 1) * 64;   // row (n) offset within tile
  const int wc = (wave & 1) * 64;    // col offset within 128-col half

  for (int ph = 0; ph < 6; ++ph) {   // {Q,K,V} x {colHalf 0,1}
    const int mat = ph >> 1;
    const int colBase = (ph & 1) * 128;
    const u16* WT = mat == 0 ? WqT : (mat == 1 ? WkT : WvT);
    const float* bias = mat == 0 ? bq : (mat == 1 ? bk : bv);
    f32x4 acc[4][4] = {};

    for (int half = 0; half < 2; ++half) {
      // load this half's B-fragments straight from L2 into registers
      s16x8 breg[4][4];   // [kc2][fc]
      for (int fc = 0; fc < 4; ++fc) {
        const u16* colp = WT + (size_t)(colBase + wc + fc * 16 + l16) * 256 + quad * 8;
        for (int kc2 = 0; kc2 < 4; ++kc2)
          breg[kc2][fc] = *(const s16x8*)(colp + (half * 4 + kc2) * 32);
      }
      for (int kc2 = 0; kc2 < 4; ++kc2) {
        int kc = (half * 4 + kc2) * 32;
        s16x8 a[4];
        for (int f = 0; f < 4; ++f) a[f] = *(const s16x8*)&xs[wr + f * 16 + l16][kc + quad * 8];
        for (int fr = 0; fr < 4; ++fr)
          for (int fc = 0; fc < 4; ++fc)
            acc[fr][fc] = __builtin_amdgcn_mfma_f32_16x16x32_bf16(a[fr], breg[kc2][fc], acc[fr][fc], 0, 0, 0);
      }
    }

    // epilogue: bias (+relu for Q,K), cast bf16, store; K columns also summed
    float ksacc[4] = {0.f, 0.f, 0.f, 0.f};
    for (int fc = 0; fc < 4; ++fc) {
      int colg = colBase + wc + fc * 16 + l16;
      float bb = bias[colg];
      for (int fr = 0; fr < 4; ++fr) {
        int nl = wr + fr * 16 + quad * 4;
        int n = n0 + nl;
        if (mat == 0) {
          for (int j = 0; j < 4; ++j) {
            float v = acc[fr][fc][j] + bb;
            v = fmaxf(v, 0.f);
            Qb[(size_t)(n + j) * 256 + colg] = (n + j < N) ? f2bf(v) : (u16)0;
          }
        } else {
          u16x4 pk;
          for (int j = 0; j < 4; ++j) {
            float v = acc[fr][fc][j] + bb;
            if (mat == 1) v = fmaxf(v, 0.f);
            bool ok = (n + j < N);
            pk[j] = ok ? f2bf(v) : (u16)0;
            if (mat == 1) ksacc[fc] += ok ? v : 0.f;
          }
          u16* T = (mat == 1) ? Kt : Vt;
          *(u16x4*)&T[(size_t)colg * NPAD + n] = pk;
        }
      }
    }
    if (mat == 1) {
      // reduce ksacc over the 4 quads (lanes differing in bits 4,5), then LDS-accumulate
      for (int fc = 0; fc < 4; ++fc) {
        float v = ksacc[fc];
        v += __shfl_xor(v, 16);
        v += __shfl_xor(v, 32);
        if (quad == 0) atomicAdd(&ksl[colBase + wc + fc * 16 + l16], v);
      }
    }
  }
  __syncthreads();
  atomicAdd(&ksum[tid], ksl[tid]);
}

// ---------------- Stage 3: KV^T partials with register-prefetch pipeline ----------------
// P[s][d][e] = sum over this split's n-chunks of V[n][e]*K[n][d]
__global__ __launch_bounds__(256, 2)
void kv_kernel(const u16* __restrict__ Kt, const u16* __restrict__ Vt,
               float* __restrict__ P, int NPAD) {
  __shared__ u16 As[128 * 32];   // Vt rows (e), [row][32k] no pad
  __shared__ u16 Bs[128 * 32];   // Kt rows (d)
  const int tid = threadIdx.x;
  const int s = blockIdx.x & 63;
  const int tile = blockIdx.x >> 6;
  const int ti = (tile >> 1) * 128;  // e base
  const int tj = (tile & 1) * 128;   // d base
  const int wave = tid >> 6, lane = tid & 63;
  const int quad = lane >> 4, l16 = lane & 15;
  const int we = (wave >> 1) * 64;
  const int wd = (wave & 1) * 64;
  f32x4 acc[4][4] = {};
  const int NCH = NPAD >> 5;

  // staging map: idx = tid*2+i -> row=idx>>2, seg=(idx&3)*8 (16B chunks)
  int row0 = (tid * 2) >> 2, seg0 = ((tid * 2) & 3) * 8;
  int row1 = (tid * 2 + 1) >> 2, seg1 = ((tid * 2 + 1) & 3) * 8;

  s16x8 ra0, ra1, rb0, rb1;
  int c = s;
  if (c < NCH) {
    int nb = c << 5;
    ra0 = *(const s16x8*)&Vt[(size_t)(ti + row0) * NPAD + nb + seg0];
    ra1 = *(const s16x8*)&Vt[(size_t)(ti + row1) * NPAD + nb + seg1];
    rb0 = *(const s16x8*)&Kt[(size_t)(tj + row0) * NPAD + nb + seg0];
    rb1 = *(const s16x8*)&Kt[(size_t)(tj + row1) * NPAD + nb + seg1];
  }
  for (; c < NCH; c += 64) {
    __syncthreads();   // previous iter's LDS reads complete
    *(s16x8*)&As[row0 * 32 + seg0] = ra0;
    *(s16x8*)&As[row1 * 32 + seg1] = ra1;
    *(s16x8*)&Bs[row0 * 32 + seg0] = rb0;
    *(s16x8*)&Bs[row1 * 32 + seg1] = rb1;
    __syncthreads();
    int cn = c + 64;
    if (cn < NCH) {    // prefetch next chunk; latency hidden under MFMAs
      int nb = cn << 5;
      ra0 = *(const s16x8*)&Vt[(size_t)(ti + row0) * NPAD + nb + seg0];
      ra1 = *(const s16x8*)&Vt[(size_t)(ti + row1) * NPAD + nb + seg1];
      rb0 = *(const s16x8*)&Kt[(size_t)(tj + row0) * NPAD + nb + seg0];
      rb1 = *(const s16x8*)&Kt[(size_t)(tj + row1) * NPAD + nb + seg1];
    }
    s16x8 a[4], b[4];
    for (int f = 0; f < 4; ++f) a[f] = *(const s16x8*)&As[(we + f * 16 + l16) * 32 + quad * 8];
    for (int f = 0; f < 4; ++f) b[f] = *(const s16x8*)&Bs[(wd + f * 16 + l16) * 32 + quad * 8];
    for (int fr = 0; fr < 4; ++fr)
      for (int fc = 0; fc < 4; ++fc)
        acc[fr][fc] = __builtin_amdgcn_mfma_f32_16x16x32_bf16(a[fr], b[fc], acc[fr][fc], 0, 0, 0);
  }
  float* Pp = P + (size_t)s * 65536;
  for (int fr = 0; fr < 4; ++fr)
    for (int fc = 0; fc < 4; ++fc) {
      int d = tj + wd + fc * 16 + l16;
      int e0 = ti + we + fr * 16 + quad * 4;
      *(f32x4*)&Pp[(size_t)d * 256 + e0] = acc[fr][fc];
    }
}

// ---------------- Stage 4: reduce partials, emit KVtb[e][d] bf16 ----------------
__global__ void kvred_kernel(const float* __restrict__ P, u16* __restrict__ KVtb) {
  int d = blockIdx.x;
  int e = threadIdx.x;
  float s = 0.f;
  for (int sp = 0; sp < 64; ++sp) s += P[(size_t)sp * 65536 + d * 256 + e];
  KVtb[e * 256 + d] = f2bf(s);
}

// ---------------- Stage 5: out[r][e] = (Q@KV)[r][e] / (Q[r].ksum + eps), KV in registers ----------------
__global__ __launch_bounds__(256, 2)
void out_kernel(const u16* __restrict__ Qb, const u16* __restrict__ KVtb,
                const float* __restrict__ ksum, float* __restrict__ out,
                int N, int NPAD) {
  __shared__ u16 Qs[128][264];
  __shared__ float nrm[128];
  __shared__ float ks[256];
  __shared__ float nrmp[256];
  const int tid = threadIdx.x;
  const int r0 = blockIdx.x * 128;

  for (int i = 0; i < 16; ++i) {
    int l = tid + i * 256;
    int row = l >> 5;
    int seg = (l & 31) << 3;
    *(s16x8*)&Qs[row][seg] = *(const s16x8*)&Qb[(size_t)(r0 + row) * 256 + seg];
  }
  ks[tid] = ksum[tid];
  __syncthreads();

  // normalizer: 2 threads per row, vectorized LDS reads
  {
    int r = tid & 127, h = tid >> 7;
    float sa = 0.f;
    for (int d = h * 128; d < h * 128 + 128; d += 8) {
      s16x8 q = *(const s16x8*)&Qs[r][d];
      for (int j = 0; j < 8; ++j) sa += bf2f((u16)q[j]) * ks[d + j];
    }
    nrmp[tid] = sa;
  }
  __syncthreads();
  if (tid < 128) nrm[tid] = nrmp[tid] + nrmp[tid + 128] + EPS;
  __syncthreads();

  const int wave = tid >> 6, lane = tid & 63;
  const int quad = lane >> 4, l16 = lane & 15;
  const int we = (wave >> 1) * 64;    // e offset within 128-half
  const int wrw = (wave & 1) * 64;    // r offset
  for (int eh = 0; eh < 2; ++eh) {
    f32x4 acc[4][4] = {};
    for (int half = 0; half < 2; ++half) {
      s16x8 areg[4][4];   // [kc2][fr] KV fragments from L2
      for (int fr = 0; fr < 4; ++fr) {
        const u16* rowp = KVtb + (size_t)(eh * 128 + we + fr * 16 + l16) * 256 + quad * 8;
        for (int kc2 = 0; kc2 < 4; ++kc2)
          areg[kc2][fr] = *(const s16x8*)(rowp + (half * 4 + kc2) * 32);
      }
      for (int kc2 = 0; kc2 < 4; ++kc2) {
        int kc = (half * 4 + kc2) * 32;
        s16x8 b[4];
        for (int f = 0; f < 4; ++f) b[f] = *(const s16x8*)&Qs[wrw + f * 16 + l16][kc + quad * 8];
        for (int fr = 0; fr < 4; ++fr)
          for (int fc = 0; fc < 4; ++fc)
            acc[fr][fc] = __builtin_amdgcn_mfma_f32_16x16x32_bf16(areg[kc2][fr], b[fc], acc[fr][fc], 0, 0, 0);
      }
    }
    for (int fc = 0; fc < 4; ++fc) {
      int rl = wrw + fc * 16 + l16;
      int rg = r0 + rl;
      float inv = 1.0f / nrm[rl];
      if (rg < N) {
        for (int fr = 0; fr < 4; ++fr) {
          int eg = eh * 128 + we + fr * 16 + quad * 4;
          f32x4 o;
          o[0] = acc[fr][fc][0] * inv;
          o[1] = acc[fr][fc][1] * inv;
          o[2] = acc[fr][fc][2] * inv;
          o[3] = acc[fr][fc][3] * inv;
          *(f32x4*)&out[(size_t)rg * 256 + eg] = o;
        }
      }
    }
  }
}

extern "C" void kernel_launch(void* const* d_in, const int* in_sizes, int n_in,
                              void* d_out, int out_size, void* d_ws, size_t ws_size,
                              hipStream_t stream) {
  const float* x  = (const float*)d_in[0];
  const float* Wq = (const float*)d_in[1];
  const float* bq = (const float*)d_in[2];
  const float* Wk = (const float*)d_in[3];
  const float* bk = (const float*)d_in[4];
  const float* Wv = (const float*)d_in[5];
  const float* bv = (const float*)d_in[6];
  float* out = (float*)d_out;

  int N = in_sizes[0] / 256;
  int NPAD = ((N + 127) / 128) * 128;
  int nblk = NPAD / 128;

  char* p = (char*)d_ws;
  size_t szT = (size_t)256 * NPAD * sizeof(u16);
  u16* Kt = (u16*)p; p += szT;
  u16* Vt = (u16*)p; p += szT;
  u16* Qb = (u16*)p; p += szT;
  float* P = (float*)p; p += (size_t)64 * 65536 * sizeof(float);
  u16* KVtb = (u16*)p; p += (size_t)65536 * sizeof(u16);
  float* ksum = (float*)p; p += 256 * sizeof(float);
  u16* WqT = (u16*)p; p += (size_t)65536 * sizeof(u16);
  u16* WkT = (u16*)p; p += (size_t)65536 * sizeof(u16);
  u16* WvT = (u16*)p; p += (size_t)65536 * sizeof(u16);

  hipMemsetAsync(ksum, 0, 256 * sizeof(float), stream);
  wtrans_kernel<<<48, 256, 0, stream>>>(Wq, Wk, Wv, WqT, WkT, WvT);
  qkv_kernel<<<nblk, 256, 0, stream>>>(x, WqT, WkT, WvT, bq, bk, bv, Qb, Kt, Vt, ksum, N, NPAD);
  kv_kernel<<<256, 256, 0, stream>>>(Kt, Vt, P, NPAD);
  kvred_kernel<<<256, 256, 0, stream>>>(P, KVtb);
  out_kernel<<<nblk, 256, 0, stream>>>(Qb, KVtb, ksum, out, N, NPAD);
}

// Round 3
// 376.452 us; speedup vs baseline: 1.2502x; 1.2502x over previous
//
#include <hip/hip_runtime.h>

typedef unsigned short u16;
typedef float f32x4 __attribute__((ext_vector_type(4)));
typedef short s16x8 __attribute__((ext_vector_type(8)));
typedef unsigned short u16x4 __attribute__((ext_vector_type(4)));

#define EPS 1e-6f

static __device__ __forceinline__ u16 f2bf(float f) {
  unsigned u = __float_as_uint(f);
  u += 0x7fffu + ((u >> 16) & 1u);   // RNE
  return (u16)(u >> 16);
}
static __device__ __forceinline__ float bf2f(u16 h) {
  return __uint_as_float(((unsigned)h) << 16);
}

// ---------------- Stage 1: transpose weights to bf16 [col][k] ----------------
__global__ void wtrans_kernel(const float* __restrict__ Wq, const float* __restrict__ Wk,
                              const float* __restrict__ Wv,
                              u16* __restrict__ WqT, u16* __restrict__ WkT, u16* __restrict__ WvT) {
  int b = blockIdx.x;
  int mat = b >> 4, cg = b & 15;
  const float* W = mat == 0 ? Wq : (mat == 1 ? Wk : Wv);
  u16* WT = mat == 0 ? WqT : (mat == 1 ? WkT : WvT);
  int t = threadIdx.x;
  int c = cg * 16 + (t & 15);
  int k0 = (t >> 4) * 16;
  for (int i = 0; i < 16; ++i) {
    int k = k0 + i;
    WT[c * 256 + k] = f2bf(W[k * 256 + c]);
  }
}

// ---------------- Stage 2: Q,K,V GEMMs ----------------
// Coalesced LDS weight staging (R1) + one-chunk-ahead register prefetch of the
// next 8KB weight chunk (vmcnt wait covered by MFMAs). Fused ksum epilogue.
__global__ __launch_bounds__(256, 2)
void qkv_kernel(const float* __restrict__ x,
                const u16* __restrict__ WqT, const u16* __restrict__ WkT, const u16* __restrict__ WvT,
                const float* __restrict__ bq, const float* __restrict__ bk, const float* __restrict__ bv,
                u16* __restrict__ Qb, u16* __restrict__ Kt, u16* __restrict__ Vt,
                float* __restrict__ ksum, int N, int NPAD) {
  __shared__ u16 xs[128][264];   // x tile bf16, +8 pad
  __shared__ u16 wst[128][40];   // weight chunk [col][k32 + 8 pad]
  __shared__ float ksl[256];     // block-local K column sums
  const int tid = threadIdx.x;
  const int n0 = blockIdx.x * 128;

  ksl[tid] = 0.f;

  // stage x tile (fp32 -> bf16), packed 8B LDS writes
  for (int i = 0; i < 32; ++i) {
    int l = tid + i * 256;
    int row = l >> 6;
    int c4 = (l & 63) << 2;
    int n = n0 + row;
    float4 v = make_float4(0.f, 0.f, 0.f, 0.f);
    if (n < N) v = *(const float4*)(x + (size_t)n * 256 + c4);
    u16x4 pk;
    pk[0] = f2bf(v.x); pk[1] = f2bf(v.y); pk[2] = f2bf(v.z); pk[3] = f2bf(v.w);
    *(u16x4*)&xs[row][c4] = pk;
  }

  const int wave = tid >> 6, lane = tid & 63;
  const int quad = lane >> 4, l16 = lane & 15;
  const int wr = (wave >> 1) * 64;   // row (n) offset within tile
  const int wc = (wave & 1) * 64;    // col offset within 128-col half

  // weight-chunk staging map: thread loads 32B: col = tid>>1, seg = (tid&1)*16
  const int scol = tid >> 1, sseg = (tid & 1) * 16;

  // prefetch chunk it=0 (phase 0, kc 0)
  s16x8 w0, w1;
  {
    const u16* p = WqT + (size_t)scol * 256 + sseg;
    w0 = *(const s16x8*)p;
    w1 = *(const s16x8*)(p + 8);
  }

  f32x4 acc[4][4] = {};
  for (int it = 0; it < 48; ++it) {
    const int ph = it >> 3, kc = (it & 7) * 32;
    const int mat = ph >> 1;
    const int colBase = (ph & 1) * 128;

    __syncthreads();                 // readers of previous chunk done (also covers xs on it==0)
    *(s16x8*)&wst[scol][sseg] = w0;
    *(s16x8*)&wst[scol][sseg + 8] = w1;
    __syncthreads();

    // prefetch next chunk (possibly next phase's matrix)
    if (it + 1 < 48) {
      int itn = it + 1;
      int phn = itn >> 3, kcn = (itn & 7) * 32;
      int matn = phn >> 1, colBn = (phn & 1) * 128;
      const u16* WTn = matn == 0 ? WqT : (matn == 1 ? WkT : WvT);
      const u16* p = WTn + (size_t)(colBn + scol) * 256 + kcn + sseg;
      w0 = *(const s16x8*)p;
      w1 = *(const s16x8*)(p + 8);
    }

    // MFMA on current chunk
    s16x8 a[4], b[4];
    for (int f = 0; f < 4; ++f) a[f] = *(const s16x8*)&xs[wr + f * 16 + l16][kc + quad * 8];
    for (int f = 0; f < 4; ++f) b[f] = *(const s16x8*)&wst[wc + f * 16 + l16][quad * 8];
    for (int fr = 0; fr < 4; ++fr)
      for (int fc = 0; fc < 4; ++fc)
        acc[fr][fc] = __builtin_amdgcn_mfma_f32_16x16x32_bf16(a[fr], b[fc], acc[fr][fc], 0, 0, 0);

    if ((it & 7) == 7) {
      // ---- phase epilogue ----
      const float* bias = mat == 0 ? bq : (mat == 1 ? bk : bv);
      float ksacc[4] = {0.f, 0.f, 0.f, 0.f};
      for (int fc = 0; fc < 4; ++fc) {
        int colg = colBase + wc + fc * 16 + l16;
        float bb = bias[colg];
        for (int fr = 0; fr < 4; ++fr) {
          int nl = wr + fr * 16 + quad * 4;
          int n = n0 + nl;
          if (mat == 0) {
            for (int j = 0; j < 4; ++j) {
              float v = acc[fr][fc][j] + bb;
              v = fmaxf(v, 0.f);
              Qb[(size_t)(n + j) * 256 + colg] = (n + j < N) ? f2bf(v) : (u16)0;
            }
          } else {
            u16x4 pk;
            for (int j = 0; j < 4; ++j) {
              float v = acc[fr][fc][j] + bb;
              if (mat == 1) v = fmaxf(v, 0.f);
              bool ok = (n + j < N);
              pk[j] = ok ? f2bf(v) : (u16)0;
              if (mat == 1) ksacc[fc] += ok ? v : 0.f;
            }
            u16* T = (mat == 1) ? Kt : Vt;
            *(u16x4*)&T[(size_t)colg * NPAD + n] = pk;
          }
        }
      }
      if (mat == 1) {
        for (int fc = 0; fc < 4; ++fc) {
          float v = ksacc[fc];
          v += __shfl_xor(v, 16);
          v += __shfl_xor(v, 32);
          if (quad == 0) atomicAdd(&ksl[colBase + wc + fc * 16 + l16], v);
        }
      }
      // reset accumulators for next phase
      for (int fr = 0; fr < 4; ++fr)
        for (int fc = 0; fc < 4; ++fc)
          acc[fr][fc] = (f32x4){0.f, 0.f, 0.f, 0.f};
    }
  }
  __syncthreads();
  atomicAdd(&ksum[tid], ksl[tid]);
}

// ---------------- Stage 3: KV^T partials with register-prefetch pipeline ----------------
__global__ __launch_bounds__(256, 2)
void kv_kernel(const u16* __restrict__ Kt, const u16* __restrict__ Vt,
               float* __restrict__ P, int NPAD) {
  __shared__ u16 As[128][40];   // Vt rows (e), +8 pad
  __shared__ u16 Bs[128][40];   // Kt rows (d)
  const int tid = threadIdx.x;
  const int s = blockIdx.x & 63;
  const int tile = blockIdx.x >> 6;
  const int ti = (tile >> 1) * 128;  // e base
  const int tj = (tile & 1) * 128;   // d base
  const int wave = tid >> 6, lane = tid & 63;
  const int quad = lane >> 4, l16 = lane & 15;
  const int we = (wave >> 1) * 64;
  const int wd = (wave & 1) * 64;
  f32x4 acc[4][4] = {};
  const int NCH = NPAD >> 5;

  int row0 = (tid * 2) >> 2, seg0 = ((tid * 2) & 3) * 8;
  int row1 = (tid * 2 + 1) >> 2, seg1 = ((tid * 2 + 1) & 3) * 8;

  s16x8 ra0, ra1, rb0, rb1;
  int c = s;
  if (c < NCH) {
    int nb = c << 5;
    ra0 = *(const s16x8*)&Vt[(size_t)(ti + row0) * NPAD + nb + seg0];
    ra1 = *(const s16x8*)&Vt[(size_t)(ti + row1) * NPAD + nb + seg1];
    rb0 = *(const s16x8*)&Kt[(size_t)(tj + row0) * NPAD + nb + seg0];
    rb1 = *(const s16x8*)&Kt[(size_t)(tj + row1) * NPAD + nb + seg1];
  }
  for (; c < NCH; c += 64) {
    __syncthreads();
    *(s16x8*)&As[row0][seg0] = ra0;
    *(s16x8*)&As[row1][seg1] = ra1;
    *(s16x8*)&Bs[row0][seg0] = rb0;
    *(s16x8*)&Bs[row1][seg1] = rb1;
    __syncthreads();
    int cn = c + 64;
    if (cn < NCH) {
      int nb = cn << 5;
      ra0 = *(const s16x8*)&Vt[(size_t)(ti + row0) * NPAD + nb + seg0];
      ra1 = *(const s16x8*)&Vt[(size_t)(ti + row1) * NPAD + nb + seg1];
      rb0 = *(const s16x8*)&Kt[(size_t)(tj + row0) * NPAD + nb + seg0];
      rb1 = *(const s16x8*)&Kt[(size_t)(tj + row1) * NPAD + nb + seg1];
    }
    s16x8 a[4], b[4];
    for (int f = 0; f < 4; ++f) a[f] = *(const s16x8*)&As[we + f * 16 + l16][quad * 8];
    for (int f = 0; f < 4; ++f) b[f] = *(const s16x8*)&Bs[wd + f * 16 + l16][quad * 8];
    for (int fr = 0; fr < 4; ++fr)
      for (int fc = 0; fc < 4; ++fc)
        acc[fr][fc] = __builtin_amdgcn_mfma_f32_16x16x32_bf16(a[fr], b[fc], acc[fr][fc], 0, 0, 0);
  }
  float* Pp = P + (size_t)s * 65536;
  for (int fr = 0; fr < 4; ++fr)
    for (int fc = 0; fc < 4; ++fc) {
      int d = tj + wd + fc * 16 + l16;
      int e0 = ti + we + fr * 16 + quad * 4;
      *(f32x4*)&Pp[(size_t)d * 256 + e0] = acc[fr][fc];
    }
}

// ---------------- Stage 4: reduce partials, emit KVtb[e][d] bf16 ----------------
__global__ void kvred_kernel(const float* __restrict__ P, u16* __restrict__ KVtb) {
  int d = blockIdx.x;
  int e = threadIdx.x;
  float s = 0.f;
  for (int sp = 0; sp < 64; ++sp) s += P[(size_t)sp * 65536 + d * 256 + e];
  KVtb[e * 256 + d] = f2bf(s);
}

// ---------------- Stage 5: out[r][e] = (Q@KV)[r][e] / (Q[r].ksum + eps) ----------------
// KV staged in LDS chunks (coalesced) with one-chunk-ahead register prefetch.
__global__ __launch_bounds__(256, 2)
void out_kernel(const u16* __restrict__ Qb, const u16* __restrict__ KVtb,
                const float* __restrict__ ksum, float* __restrict__ out,
                int N, int NPAD) {
  __shared__ u16 Qs[128][264];
  __shared__ u16 KVs[128][40];
  __shared__ float nrm[128];
  __shared__ float ks[256];
  __shared__ float nrmp[256];
  const int tid = threadIdx.x;
  const int r0 = blockIdx.x * 128;

  for (int i = 0; i < 16; ++i) {
    int l = tid + i * 256;
    int row = l >> 5;
    int seg = (l & 31) << 3;
    *(s16x8*)&Qs[row][seg] = *(const s16x8*)&Qb[(size_t)(r0 + row) * 256 + seg];
  }
  ks[tid] = ksum[tid];
  __syncthreads();

  // normalizer: 2 threads per row
  {
    int r = tid & 127, h = tid >> 7;
    float sa = 0.f;
    for (int d = h * 128; d < h * 128 + 128; d += 8) {
      s16x8 q = *(const s16x8*)&Qs[r][d];
      for (int j = 0; j < 8; ++j) sa += bf2f((u16)q[j]) * ks[d + j];
    }
    nrmp[tid] = sa;
  }
  __syncthreads();
  if (tid < 128) nrm[tid] = nrmp[tid] + nrmp[tid + 128] + EPS;

  const int wave = tid >> 6, lane = tid & 63;
  const int quad = lane >> 4, l16 = lane & 15;
  const int we = (wave >> 1) * 64;    // e offset within 128-half
  const int wrw = (wave & 1) * 64;    // r offset
  const int scol = tid >> 1, sseg = (tid & 1) * 16;   // staging map

  // prefetch chunk it=0 (eh=0, kc=0): KVtb rows are e, cols are d
  s16x8 w0, w1;
  {
    const u16* p = KVtb + (size_t)scol * 256 + sseg;
    w0 = *(const s16x8*)p;
    w1 = *(const s16x8*)(p + 8);
  }

  f32x4 acc[4][4] = {};
  for (int it = 0; it < 16; ++it) {
    const int eh = it >> 3, kc = (it & 7) * 32;

    __syncthreads();
    *(s16x8*)&KVs[scol][sseg] = w0;
    *(s16x8*)&KVs[scol][sseg + 8] = w1;
    __syncthreads();

    if (it + 1 < 16) {
      int itn = it + 1;
      int ehn = itn >> 3, kcn = (itn & 7) * 32;
      const u16* p = KVtb + (size_t)(ehn * 128 + scol) * 256 + kcn + sseg;
      w0 = *(const s16x8*)p;
      w1 = *(const s16x8*)(p + 8);
    }

    s16x8 a[4], b[4];
    for (int f = 0; f < 4; ++f) a[f] = *(const s16x8*)&KVs[we + f * 16 + l16][quad * 8];
    for (int f = 0; f < 4; ++f) b[f] = *(const s16x8*)&Qs[wrw + f * 16 + l16][kc + quad * 8];
    for (int fr = 0; fr < 4; ++fr)
      for (int fc = 0; fc < 4; ++fc)
        acc[fr][fc] = __builtin_amdgcn_mfma_f32_16x16x32_bf16(a[fr], b[fc], acc[fr][fc], 0, 0, 0);

    if ((it & 7) == 7) {
      for (int fc = 0; fc < 4; ++fc) {
        int rl = wrw + fc * 16 + l16;
        int rg = r0 + rl;
        float inv = 1.0f / nrm[rl];
        if (rg < N) {
          for (int fr = 0; fr < 4; ++fr) {
            int eg = eh * 128 + we + fr * 16 + quad * 4;
            f32x4 o;
            o[0] = acc[fr][fc][0] * inv;
            o[1] = acc[fr][fc][1] * inv;
            o[2] = acc[fr][fc][2] * inv;
            o[3] = acc[fr][fc][3] * inv;
            *(f32x4*)&out[(size_t)rg * 256 + eg] = o;
          }
        }
      }
      for (int fr = 0; fr < 4; ++fr)
        for (int fc = 0; fc < 4; ++fc)
          acc[fr][fc] = (f32x4){0.f, 0.f, 0.f, 0.f};
    }
  }
}

extern "C" void kernel_launch(void* const* d_in, const int* in_sizes, int n_in,
                              void* d_out, int out_size, void* d_ws, size_t ws_size,
                              hipStream_t stream) {
  const float* x  = (const float*)d_in[0];
  const float* Wq = (const float*)d_in[1];
  const float* bq = (const float*)d_in[2];
  const float* Wk = (const float*)d_in[3];
  const float* bk = (const float*)d_in[4];
  const float* Wv = (const float*)d_in[5];
  const float* bv = (const float*)d_in[6];
  float* out = (float*)d_out;

  int N = in_sizes[0] / 256;
  int NPAD = ((N + 127) / 128) * 128;
  int nblk = NPAD / 128;

  char* p = (char*)d_ws;
  size_t szT = (size_t)256 * NPAD * sizeof(u16);
  u16* Kt = (u16*)p; p += szT;
  u16* Vt = (u16*)p; p += szT;
  u16* Qb = (u16*)p; p += szT;
  float* P = (float*)p; p += (size_t)64 * 65536 * sizeof(float);
  u16* KVtb = (u16*)p; p += (size_t)65536 * sizeof(u16);
  float* ksum = (float*)p; p += 256 * sizeof(float);
  u16* WqT = (u16*)p; p += (size_t)65536 * sizeof(u16);
  u16* WkT = (u16*)p; p += (size_t)65536 * sizeof(u16);
  u16* WvT = (u16*)p; p += (size_t)65536 * sizeof(u16);

  hipMemsetAsync(ksum, 0, 256 * sizeof(float), stream);
  wtrans_kernel<<<48, 256, 0, stream>>>(Wq, Wk, Wv, WqT, WkT, WvT);
  qkv_kernel<<<nblk, 256, 0, stream>>>(x, WqT, WkT, WvT, bq, bk, bv, Qb, Kt, Vt, ksum, N, NPAD);
  kv_kernel<<<256, 256, 0, stream>>>(Kt, Vt, P, NPAD);
  kvred_kernel<<<256, 256, 0, stream>>>(P, KVtb);
  out_kernel<<<nblk, 256, 0, stream>>>(Qb, KVtb, ksum, out, N, NPAD);
}